// Round 3
// baseline (690.787 us; speedup 1.0000x reference)
//
#include <hip/hip_runtime.h>
#include <hip/hip_bf16.h>
#include <stdint.h>

typedef __bf16 bf16x8 __attribute__((ext_vector_type(8)));
typedef __bf16 bf16x4 __attribute__((ext_vector_type(4)));
typedef float floatx4 __attribute__((ext_vector_type(4)));

typedef __attribute__((address_space(1))) void gvoid;
typedef __attribute__((address_space(3))) void lvoid;

__device__ __forceinline__ void async_load16(const __bf16* g, __bf16* l) {
  __builtin_amdgcn_global_load_lds((gvoid*)g, (lvoid*)l, 16, 0, 0);
}

__device__ __forceinline__ bf16x8 ld8(const float* p) {
  const floatx4 a = *(const floatx4*)p;
  const floatx4 b = *(const floatx4*)(p + 4);
  bf16x8 r;
  r[0] = (__bf16)a[0]; r[1] = (__bf16)a[1];
  r[2] = (__bf16)a[2]; r[3] = (__bf16)a[3];
  r[4] = (__bf16)b[0]; r[5] = (__bf16)b[1];
  r[6] = (__bf16)b[2]; r[7] = (__bf16)b[3];
  return r;
}

// fp32 -> bf16 elementwise (n multiple of 2048)
__global__ __launch_bounds__(256) void cvt_kernel(const float* __restrict__ in,
                                                  __bf16* __restrict__ out,
                                                  int n) {
  const int i = (blockIdx.x * 256 + threadIdx.x) * 8;
  if (i < n) *(bf16x8*)(out + i) = ld8(in + i);
}

// ---------------------------------------------------------------------------
// gemm128: pipelined 128x256 BK=64 GEMM (counted-vmcnt schedule, T3+T4+T5).
// C = A * Bt^T (+bias/epilogue). A:[M,K] bf16 stride K; Bt:[N,K] bf16 stride
// ldb. 512 thr = 8 waves (2M x 4N); wave out 64x64 via acc[4][4] 16x16x32.
// LDS 96 KiB: AS[2 dbuf][2 khalf][128x32], BS[2][2][256x32].
// Per K-tile (64): 2 phases (kh). Each phase: issue 3 stages of tile T+1's
// kh-half (A 1 call, B 2 calls) -> buf^1; ds_read 8 frags of tile T; barrier;
// lgkmcnt(0); 16 MFMA (setprio 1); counted vmcnt; barrier.
// vmcnt ledger (3 loads per half-stage): prologue 6 issued, vmcnt(3) ->
// tile0-kh0 landed. Steady p=0: outstanding [Tkh1(3), T+1kh0(3)] -> vmcnt(3)
// retires T-kh1 (needed p=1). p=1: [T+1kh0(3), T+1kh1(3)] -> vmcnt(3)
// retires T+1-kh0 (needed next tile). LAST tile p=0: nothing issued ->
// vmcnt(0) (tail-race fix). Never drains the pipe mid-loop otherwise.
// Swizzle (bank-spread frag reads): 16B granule of logical (row, gc) stored
// at gc ^ xf(row), xf(row) = (row&3) ^ ((row>>2)&1). Applied on the per-lane
// GLOBAL source (gload_lds LDS dest stays linear, rule 21) and on the
// ds_read column (xq). Verified element-wise for both A and B maps.
// EPI: 0 QKV (q cols scaled 0.125, vT scatter), 1 +bias+resf(fp32),
// 2 relu(+bias), 3 +resb(bf16), 4 +bias+resb(bf16).
// ---------------------------------------------------------------------------
template <int EPI>
__global__ __launch_bounds__(512, 2) void gemm128(
    const __bf16* __restrict__ A, const __bf16* __restrict__ Bt,
    const float* __restrict__ bias, const float* __restrict__ resf,
    const __bf16* __restrict__ resb, __bf16* __restrict__ o0,
    __bf16* __restrict__ o2, int M, int N, int K, int ldb) {
  __shared__ __align__(16) __bf16 AS[2][2][4096];  // [buf][kh][128*32]
  __shared__ __align__(16) __bf16 BS[2][2][8192];  // [buf][kh][256*32]
  const int tid = threadIdx.x;
  const int w = tid >> 6;        // 0..7
  const int lane = tid & 63;
  const int l16 = lane & 15;
  const int quad = lane >> 4;
  const int wm = w >> 2;         // 0..1 : 64-row block
  const int wn = w & 3;          // 0..3 : 64-col block
  const int bm = blockIdx.y * 128;
  const int bn = blockIdx.x * 256;
  const int NT = K >> 6;         // K-tiles of 64

  floatx4 acc[4][4];
#pragma unroll
  for (int i = 0; i < 4; ++i)
#pragma unroll
    for (int j = 0; j < 4; ++j) acc[i][j] = (floatx4){0.f, 0.f, 0.f, 0.f};

  // staging source (per-lane, pre-swizzled): granule G = w*64+lane covers
  // row = G>>2 = w*16 + (lane>>2), logical gc = lane&3; source col gc^xf(row)
  const int xfs = ((lane >> 2) & 3) ^ ((lane >> 4) & 1);  // == xf(strow)
  const int strow = w * 16 + (lane >> 2);                 // 0..127
  const int stcol = ((lane & 3) ^ xfs) * 8;
  const __bf16* stA = A + (int64_t)(bm + strow) * K + stcol;
  const __bf16* stB0 = Bt + (int64_t)(bn + strow) * ldb + stcol;
  const __bf16* stB1 = stB0 + (int64_t)128 * ldb;

  // fragment read bases: row's xf reduces to (l16&3)^((l16>>2)&1)
  const int xq = quad ^ (l16 & 3) ^ ((l16 >> 2) & 1);
  const int ard = (wm * 64 + l16) * 32 + xq * 8;  // + mi*512
  const int brd = (wn * 64 + l16) * 32 + xq * 8;  // + ni*512

  // prologue: stage tile 0 (kh0: A,B0,B1 then kh1: A,B0,B1)
  async_load16(stA, &AS[0][0][w * 512]);
  async_load16(stB0, &BS[0][0][w * 512]);
  async_load16(stB1, &BS[0][0][4096 + w * 512]);
  async_load16(stA + 32, &AS[0][1][w * 512]);
  async_load16(stB0 + 32, &BS[0][1][w * 512]);
  async_load16(stB1 + 32, &BS[0][1][4096 + w * 512]);
  asm volatile("s_waitcnt vmcnt(3)" ::: "memory");  // kh0 landed (own wave)
  __builtin_amdgcn_s_barrier();                     // -> all waves' kh0 in LDS
  __builtin_amdgcn_sched_barrier(0);

  for (int T = 0; T < NT; ++T) {
    const int buf = T & 1;
#pragma unroll
    for (int p = 0; p < 2; ++p) {
      const int kh = p;
      if (T + 1 < NT) {  // stage tile T+1's kh-half into buf^1
        const int koff = (T + 1) * 64 + kh * 32;
        async_load16(stA + koff, &AS[buf ^ 1][kh][w * 512]);
        async_load16(stB0 + koff, &BS[buf ^ 1][kh][w * 512]);
        async_load16(stB1 + koff, &BS[buf ^ 1][kh][4096 + w * 512]);
      }
      bf16x8 af[4], bfr[4];
#pragma unroll
      for (int i = 0; i < 4; ++i) {
        af[i] = *(const bf16x8*)&AS[buf][kh][ard + i * 512];
        bfr[i] = *(const bf16x8*)&BS[buf][kh][brd + i * 512];
      }
      __builtin_amdgcn_sched_barrier(0);
      __builtin_amdgcn_s_barrier();
      asm volatile("s_waitcnt lgkmcnt(0)" ::: "memory");
      __builtin_amdgcn_sched_barrier(0);
      __builtin_amdgcn_s_setprio(1);
#pragma unroll
      for (int mi = 0; mi < 4; ++mi)
#pragma unroll
        for (int ni = 0; ni < 4; ++ni)
          acc[mi][ni] = __builtin_amdgcn_mfma_f32_16x16x32_bf16(
              af[mi], bfr[ni], acc[mi][ni], 0, 0, 0);
      __builtin_amdgcn_s_setprio(0);
      __builtin_amdgcn_sched_barrier(0);
      // counted wait: p=0 -> tile T kh1 landed; p=1 -> tile T+1 kh0 landed.
      if (p == 0 && T + 1 >= NT)
        asm volatile("s_waitcnt vmcnt(0)" ::: "memory");  // tail fix
      else
        asm volatile("s_waitcnt vmcnt(3)" ::: "memory");
      __builtin_amdgcn_s_barrier();
      __builtin_amdgcn_sched_barrier(0);
    }
  }

  // epilogue: C/D layout col = lane&15, row = quad*4 + reg  [m89-verified]
#pragma unroll
  for (int ni = 0; ni < 4; ++ni) {
    const int gn = bn + wn * 64 + ni * 16 + l16;
    const float bv = (EPI == 3) ? 0.f : bias[gn];
#pragma unroll
    for (int ai = 0; ai < 4; ++ai) {
#pragma unroll
      for (int r = 0; r < 4; ++r) {
        const int gm = bm + wm * 64 + ai * 16 + quad * 4 + r;
        float v = acc[ai][ni][r] + bv;
        if (EPI == 0) {
          if (gn < 2048) {
            o0[(int64_t)gm * 2048 + gn] = (__bf16)(gn < 1024 ? v * 0.125f : v);
          } else {
            const int nn = gn - 2048, hh = nn >> 6, d = nn & 63;
            const int s = gm >> 3, b = gm & 7;  // m = s*8 + b
            o2[((b * 16 + hh) * 64 + d) * 1024 + s] = (__bf16)v;
          }
        } else {
          if (EPI == 1) v += resf[(int64_t)gm * N + gn];
          if (EPI == 3 || EPI == 4) v += (float)resb[(int64_t)gm * N + gn];
          if (EPI == 2) v = fmaxf(v, 0.f);
          o0[(int64_t)gm * N + gn] = (__bf16)v;
        }
      }
    }
  }
}

// ---------------------------------------------------------------------------
// Legacy 128x128 BK=32 GEMM (small-workspace fallback path only).
// ---------------------------------------------------------------------------
constexpr int BM = 128, BN = 128, BK = 32;

template <typename AT, typename BT, int EPI>
__global__ __launch_bounds__(256, 2) void gemm_bt(
    const AT* __restrict__ A, const BT* __restrict__ Bt,
    const float* __restrict__ bias, const float* __restrict__ resf,
    const __bf16* __restrict__ resb, __bf16* __restrict__ o0,
    __bf16* __restrict__ o2, int M, int N, int K, int ldb) {
  constexpr bool AF = sizeof(AT) == 4;
  constexpr bool BF = sizeof(BT) == 4;
  __shared__ __align__(16) __bf16 As[BM * BK];
  __shared__ __align__(16) __bf16 Bs[BN * BK];
  const int tid = threadIdx.x;
  const int w = tid >> 6;
  const int lane = tid & 63;
  const int l16 = lane & 15;
  const int quad = lane >> 4;
  const int wm = (w & 1) * 64;
  const int wn = (w >> 1) * 64;
  const int bm = blockIdx.y * BM;
  const int bn = blockIdx.x * BN;

  floatx4 acc[4][4];
#pragma unroll
  for (int i = 0; i < 4; ++i)
#pragma unroll
    for (int j = 0; j < 4; ++j) acc[i][j] = (floatx4){0.f, 0.f, 0.f, 0.f};

  const int srow = tid >> 2, scol = (tid & 3) * 8;
  const int arow = lane >> 2, acol = (lane & 3) * 8;
  const AT* Ag;
  if constexpr (AF) Ag = A + (int64_t)(bm + srow) * K + scol;
  else Ag = A + (int64_t)(bm + w * 32 + arow) * K + acol;
  const BT* Bg;
  if constexpr (BF) Bg = Bt + (int64_t)(bn + srow) * ldb + scol;
  else Bg = Bt + (int64_t)(bn + w * 32 + arow) * ldb + acol;
  __bf16* AsW = As + (w * 32) * BK;
  __bf16* BsW = Bs + (w * 32) * BK;

  bf16x8 a0, a1, b0, b1;
  if constexpr (AF) {
    a0 = ld8(Ag);
    a1 = ld8(Ag + (int64_t)64 * K);
  }
  if constexpr (BF) {
    b0 = ld8(Bg);
    b1 = ld8(Bg + (int64_t)64 * ldb);
  }

  for (int k0 = 0; k0 < K; k0 += BK) {
    __syncthreads();
    if constexpr (AF) {
      *(bf16x8*)(As + tid * 8) = a0;
      *(bf16x8*)(As + 2048 + tid * 8) = a1;
    } else {
      async_load16(Ag + k0, AsW);
      async_load16(Ag + k0 + 16 * K, AsW + 16 * BK);
    }
    if constexpr (BF) {
      *(bf16x8*)(Bs + tid * 8) = b0;
      *(bf16x8*)(Bs + 2048 + tid * 8) = b1;
    } else {
      async_load16(Bg + k0, BsW);
      async_load16(Bg + k0 + 16 * ldb, BsW + 16 * BK);
    }
    __syncthreads();
    if constexpr (AF) {
      if (k0 + BK < K) {
        a0 = ld8(Ag + k0 + BK);
        a1 = ld8(Ag + k0 + BK + (int64_t)64 * K);
      }
    }
    if constexpr (BF) {
      if (k0 + BK < K) {
        b0 = ld8(Bg + k0 + BK);
        b1 = ld8(Bg + k0 + BK + (int64_t)64 * ldb);
      }
    }
    bf16x8 af[4], bfr[4];
#pragma unroll
    for (int i = 0; i < 4; ++i) {
      af[i] = *(const bf16x8*)(As + (wm + i * 16 + l16) * BK + quad * 8);
      bfr[i] = *(const bf16x8*)(Bs + (wn + i * 16 + l16) * BK + quad * 8);
    }
#pragma unroll
    for (int mi = 0; mi < 4; ++mi)
#pragma unroll
      for (int ni = 0; ni < 4; ++ni)
        acc[mi][ni] = __builtin_amdgcn_mfma_f32_16x16x32_bf16(
            af[mi], bfr[ni], acc[mi][ni], 0, 0, 0);
  }

#pragma unroll
  for (int ni = 0; ni < 4; ++ni) {
    const int gn = bn + wn + ni * 16 + l16;
    const float bv = (EPI == 3) ? 0.f : bias[gn];
#pragma unroll
    for (int mi = 0; mi < 4; ++mi) {
#pragma unroll
      for (int r = 0; r < 4; ++r) {
        const int gm = bm + wm + mi * 16 + quad * 4 + r;
        float v = acc[mi][ni][r] + bv;
        if (EPI == 0) {
          if (gn < 2048) {
            o0[(int64_t)gm * 2048 + gn] = (__bf16)(gn < 1024 ? v * 0.125f : v);
          } else {
            const int nn = gn - 2048, hh = nn >> 6, d = nn & 63;
            const int s = gm >> 3, b = gm & 7;
            o2[((b * 16 + hh) * 64 + d) * 1024 + s] = (__bf16)v;
          }
        } else {
          if (EPI == 1) v += resf[(int64_t)gm * N + gn];
          if (EPI == 3 || EPI == 4) v += (float)resb[(int64_t)gm * N + gn];
          if (EPI == 2) v = fmaxf(v, 0.f);
          o0[(int64_t)gm * N + gn] = (__bf16)v;
        }
      }
    }
  }
}

// ---------------------------------------------------------------------------
// Flash attention, no-max softmax. Block = (bh, 128 Q rows); wave = 32 rows.
// K/V chunks (32 t) staged via global_load_lds w16, double-buffered (T14):
// one barrier per iteration, next chunk flies under compute.
// ---------------------------------------------------------------------------
__global__ __launch_bounds__(256) void attn_flash(
    const __bf16* __restrict__ qk, const __bf16* __restrict__ vT,
    __bf16* __restrict__ ctx) {
  constexpr int S = 1024, PSTR = 36;
  constexpr int ROWSTR = 8 * 2048;
  __shared__ __align__(16) __bf16 Kb[2][2048];
  __shared__ __align__(16) __bf16 Vb[2][2048];
  __shared__ __align__(16) __bf16 Pt[4][32 * PSTR];
  const int tid = threadIdx.x;
  const int w = tid >> 6;
  const int lane = tid & 63;
  const int l16 = lane & 15;
  const int quad = lane >> 4;
  const int bh = blockIdx.y, bidx = bh >> 4, h = bh & 15;
  const int qbase = blockIdx.x * 128 + w * 32;

  const __bf16* qp =
      qk + ((int64_t)(qbase + l16) * 8 + bidx) * 2048 + h * 64 + quad * 8;
  bf16x8 aq[2][2];
  aq[0][0] = *(const bf16x8*)qp;
  aq[0][1] = *(const bf16x8*)(qp + 32);
  aq[1][0] = *(const bf16x8*)(qp + 16 * ROWSTR);
  aq[1][1] = *(const bf16x8*)(qp + 16 * ROWSTR + 32);

  const __bf16* kg = qk + 1024 +
      ((int64_t)((w >> 1) * 16 + l16) * 8 + bidx) * 2048 + h * 64 +
      ((w & 1) * 4 + quad) * 8;
  const __bf16* vg =
      vT + ((int64_t)bh * 64 + w * 16 + l16) * 1024 + quad * 8;
  __bf16* pt = Pt[w];

  floatx4 o[2][4];
  float la[2][4];
#pragma unroll
  for (int rt = 0; rt < 2; ++rt)
#pragma unroll
    for (int j = 0; j < 4; ++j) {
      o[rt][j] = (floatx4){0.f, 0.f, 0.f, 0.f};
      la[rt][j] = 0.f;
    }

  async_load16(kg, Kb[0] + w * 512);
  async_load16(vg, Vb[0] + w * 512);
  int cur = 0;

  for (int t0 = 0; t0 < S; t0 += 32) {
    __syncthreads();
    if (t0 + 32 < S) {
      async_load16(kg + (int64_t)(t0 + 32) * ROWSTR, Kb[cur ^ 1] + w * 512);
      async_load16(vg + (t0 + 32), Vb[cur ^ 1] + w * 512);
    }

    bf16x8 kf[4], vv[4];
#pragma unroll
    for (int f = 0; f < 4; ++f) {
      kf[f] = *(const bf16x8*)(Kb[cur] + f * 512 + lane * 8);
      vv[f] = *(const bf16x8*)(Vb[cur] + f * 512 + lane * 8);
    }

    floatx4 s00 = (floatx4){0.f, 0.f, 0.f, 0.f};
    floatx4 s01 = (floatx4){0.f, 0.f, 0.f, 0.f};
    floatx4 s10 = (floatx4){0.f, 0.f, 0.f, 0.f};
    floatx4 s11 = (floatx4){0.f, 0.f, 0.f, 0.f};
    s00 = __builtin_amdgcn_mfma_f32_16x16x32_bf16(aq[0][0], kf[0], s00, 0, 0, 0);
    s00 = __builtin_amdgcn_mfma_f32_16x16x32_bf16(aq[0][1], kf[1], s00, 0, 0, 0);
    s01 = __builtin_amdgcn_mfma_f32_16x16x32_bf16(aq[0][0], kf[2], s01, 0, 0, 0);
    s01 = __builtin_amdgcn_mfma_f32_16x16x32_bf16(aq[0][1], kf[3], s01, 0, 0, 0);
    s10 = __builtin_amdgcn_mfma_f32_16x16x32_bf16(aq[1][0], kf[0], s10, 0, 0, 0);
    s10 = __builtin_amdgcn_mfma_f32_16x16x32_bf16(aq[1][1], kf[1], s10, 0, 0, 0);
    s11 = __builtin_amdgcn_mfma_f32_16x16x32_bf16(aq[1][0], kf[2], s11, 0, 0, 0);
    s11 = __builtin_amdgcn_mfma_f32_16x16x32_bf16(aq[1][1], kf[3], s11, 0, 0, 0);

#pragma unroll
    for (int r = 0; r < 4; ++r) {
      const int row0 = (quad * 4 + r) * PSTR;
      const float p00 = __expf(s00[r]);
      const float p01 = __expf(s01[r]);
      la[0][r] += p00 + p01;
      pt[row0 + l16] = (__bf16)p00;
      pt[row0 + 16 + l16] = (__bf16)p01;
      const int row1 = (16 + quad * 4 + r) * PSTR;
      const float p10 = __expf(s10[r]);
      const float p11 = __expf(s11[r]);
      la[1][r] += p10 + p11;
      pt[row1 + l16] = (__bf16)p10;
      pt[row1 + 16 + l16] = (__bf16)p11;
    }
    const bf16x8 pa0 = *(const bf16x8*)(pt + l16 * PSTR + quad * 8);
    const bf16x8 pa1 = *(const bf16x8*)(pt + (16 + l16) * PSTR + quad * 8);
#pragma unroll
    for (int j = 0; j < 4; ++j) {
      o[0][j] = __builtin_amdgcn_mfma_f32_16x16x32_bf16(pa0, vv[j], o[0][j], 0, 0, 0);
      o[1][j] = __builtin_amdgcn_mfma_f32_16x16x32_bf16(pa1, vv[j], o[1][j], 0, 0, 0);
    }
    cur ^= 1;
  }

#pragma unroll
  for (int rt = 0; rt < 2; ++rt)
#pragma unroll
    for (int r = 0; r < 4; ++r) {
      float s = la[rt][r];
      s += __shfl_xor(s, 1, 64);
      s += __shfl_xor(s, 2, 64);
      s += __shfl_xor(s, 4, 64);
      s += __shfl_xor(s, 8, 64);
      la[rt][r] = s;
    }
#pragma unroll
  for (int rt = 0; rt < 2; ++rt)
#pragma unroll
    for (int j = 0; j < 4; ++j)
#pragma unroll
      for (int r = 0; r < 4; ++r) {
        const int row = qbase + rt * 16 + quad * 4 + r;
        const int gm = row * 8 + bidx;
        ctx[(int64_t)gm * 1024 + h * 64 + j * 16 + l16] =
            (__bf16)(o[rt][j][r] / la[rt][r]);
      }
}

// ---------------------------------------------------------------------------
// LayerNorm over last dim (1024). One block (256 thr) per row. Vectorized.
// ---------------------------------------------------------------------------
template <typename OutT>
__global__ __launch_bounds__(256) void ln_kernel(const __bf16* __restrict__ y,
                                                 const float* __restrict__ g,
                                                 const float* __restrict__ be,
                                                 OutT* __restrict__ out) {
  constexpr int D = 1024;
  const int row = blockIdx.x;
  const int tid = threadIdx.x;
  const __bf16* yr = y + (int64_t)row * D;
  const int c0 = tid * 4;
  const bf16x4 raw = *(const bf16x4*)(yr + c0);
  float v[4];
#pragma unroll
  for (int j = 0; j < 4; ++j) v[j] = (float)raw[j];
  float s = v[0] + v[1] + v[2] + v[3];
  float sq = v[0] * v[0] + v[1] * v[1] + v[2] * v[2] + v[3] * v[3];
#pragma unroll
  for (int off = 1; off < 64; off <<= 1) {
    s += __shfl_xor(s, off, 64);
    sq += __shfl_xor(sq, off, 64);
  }
  __shared__ float ls[4], lq[4];
  const int w = tid >> 6;
  if ((tid & 63) == 0) {
    ls[w] = s;
    lq[w] = sq;
  }
  __syncthreads();
  s = ls[0] + ls[1] + ls[2] + ls[3];
  sq = lq[0] + lq[1] + lq[2] + lq[3];
  const float mean = s * (1.f / D);
  const float var = sq * (1.f / D) - mean * mean;
  const float inv = rsqrtf(var + 1e-5f);
  const floatx4 gv = *(const floatx4*)(g + c0);
  const floatx4 bv = *(const floatx4*)(be + c0);
  if constexpr (sizeof(OutT) == 4) {
    floatx4 ov;
#pragma unroll
    for (int j = 0; j < 4; ++j) ov[j] = (v[j] - mean) * inv * gv[j] + bv[j];
    *(floatx4*)((float*)out + (int64_t)row * D + c0) = ov;
  } else {
    bf16x4 ov;
#pragma unroll
    for (int j = 0; j < 4; ++j)
      ov[j] = (__bf16)((v[j] - mean) * inv * gv[j] + bv[j]);
    *(bf16x4*)((__bf16*)out + (int64_t)row * D + c0) = ov;
  }
}

// ---------------------------------------------------------------------------
// Memory map, big path (ws >= 48 MiB; d_out 32 MiB doubles as scratch):
//   QKV       qk ws[0,32)  srcb ws[32,48)   vT out[0,16)  ipwb out[16,22)
//   attn      qk (r)                        ctx -> out[16,32)
//   out-proj  owb ws[0,2)  y ws[2,18)       ctx (r), src (r)
//   LN1       y (r)                         x -> out[0,16)
//   FFN       z ws[0,16)  h ws[16,48)       x (r), w1b out[16,24), w2b out[24,32)
//             2 N-halves: h=relu(x@w1h^T+b1h) [8192,2048]; z (+)= h@w2h^T (+b2+x)
//   LN2       z (r)                         d_out fp32 [0,32)
// Grids (gemm128, all exact multiples of 256 blocks -> 100% CU fill):
//   QKV (12,64)=768, out-proj (4,64)=256, G1 (8,64)=512, G2 (4,64)=256.
// ---------------------------------------------------------------------------
extern "C" void kernel_launch(void* const* d_in, const int* in_sizes, int n_in,
                              void* d_out, int out_size, void* d_ws,
                              size_t ws_size, hipStream_t stream) {
  const float* src = (const float*)d_in[0];        // [8192,1024]
  const float* in_proj_w = (const float*)d_in[1];  // [3072,1024]
  const float* in_proj_b = (const float*)d_in[2];
  const float* out_w = (const float*)d_in[3];      // [1024,1024]
  const float* out_b = (const float*)d_in[4];
  const float* w1 = (const float*)d_in[5];         // [4096,1024]
  const float* b1 = (const float*)d_in[6];
  const float* w2 = (const float*)d_in[7];         // [1024,4096]
  const float* b2 = (const float*)d_in[8];
  const float* g1 = (const float*)d_in[9];
  const float* be1 = (const float*)d_in[10];
  const float* g2 = (const float*)d_in[11];
  const float* be2 = (const float*)d_in[12];

  char* ws = (char*)d_ws;
  char* out8 = (char*)d_out;
  __bf16* qkb = (__bf16*)ws;                       // ws[0,32M)
  __bf16* vb = (__bf16*)out8;                      // out[0,16M)
  __bf16* ipwb = (__bf16*)(out8 + (16ull << 20));  // out[16,22M)
  __bf16* srcb = (__bf16*)(ws + (32ull << 20));    // ws[32,48M)
  __bf16* ctxb = (__bf16*)(out8 + (16ull << 20));  // out[16,32M)
  __bf16* owb = (__bf16*)ws;                       // ws[0,2M)
  __bf16* yb = (__bf16*)(ws + (2ull << 20));       // ws[2,18M)
  __bf16* xb = (__bf16*)out8;                      // out[0,16M)

  const bool big = ws_size >= ((size_t)48 << 20);

  if (big) {
    __bf16* w1b = (__bf16*)(out8 + (16ull << 20));   // out[16,24M)
    __bf16* w2b = (__bf16*)(out8 + (24ull << 20));   // out[24,32M)
    __bf16* hb = (__bf16*)(ws + (16ull << 20));      // ws[16,48M) [8192,2048]
    __bf16* zb = (__bf16*)ws;                        // ws[0,16M)

    // 0/1. weight + src converts, QKV projection
    cvt_kernel<<<1536, 256, 0, stream>>>(in_proj_w, ipwb, 3 * 1024 * 1024);
    cvt_kernel<<<4096, 256, 0, stream>>>(src, srcb, 8 * 1024 * 1024);
    gemm128<0><<<dim3(12, 64), 512, 0, stream>>>(
        srcb, ipwb, in_proj_b, nullptr, nullptr, qkb, vb, 8192, 3072, 1024,
        1024);
    // 2. flash attention (ctx overwrites dead ipwb region)
    attn_flash<<<dim3(8, 128), 256, 0, stream>>>(qkb, vb, ctxb);
    // 3. out-proj + residual(src fp32)
    cvt_kernel<<<512, 256, 0, stream>>>(out_w, owb, 1024 * 1024);
    gemm128<1><<<dim3(4, 64), 512, 0, stream>>>(
        ctxb, owb, out_b, src, nullptr, yb, nullptr, 8192, 1024, 1024, 1024);
    // 4. LN1 -> x (overwrites dead vT)
    ln_kernel<__bf16><<<8192, 256, 0, stream>>>(yb, g1, be1, xb);
    // 5. FFN weights -> bf16 (ctx region dead after out-proj)
    cvt_kernel<<<2048, 256, 0, stream>>>(w1, w1b, 4 * 1024 * 1024);
    cvt_kernel<<<2048, 256, 0, stream>>>(w2, w2b, 4 * 1024 * 1024);
    // 6. FFN in 2 N=2048 halves
    for (int q = 0; q < 2; ++q) {
      gemm128<2><<<dim3(8, 64), 512, 0, stream>>>(
          xb, w1b + (int64_t)q * 2048 * 1024, b1 + q * 2048, nullptr, nullptr,
          hb, nullptr, 8192, 2048, 1024, 1024);
      if (q == 0)
        gemm128<4><<<dim3(4, 64), 512, 0, stream>>>(
            hb, w2b + q * 2048, b2, nullptr, xb, zb, nullptr, 8192, 1024, 2048,
            4096);
      else
        gemm128<3><<<dim3(4, 64), 512, 0, stream>>>(
            hb, w2b + q * 2048, nullptr, nullptr, zb, zb, nullptr, 8192, 1024,
            2048, 4096);
    }
    // 7. LN2 -> output (fp32)
    ln_kernel<float><<<8192, 256, 0, stream>>>(zb, g2, be2, (float*)d_out);
  } else {
    // fallback: legacy 128x128 path, FFN in 4 N=1024 quarters
    __bf16* w1b = (__bf16*)ws;                       // ws[0,8M)
    __bf16* w2b = (__bf16*)(ws + (8ull << 20));      // ws[8,16M)
    __bf16* hb = (__bf16*)(out8 + (16ull << 20));    // out[16,32M)
    __bf16* zb = (__bf16*)(ws + (16ull << 20));      // ws[16,32M)

    cvt_kernel<<<1536, 256, 0, stream>>>(in_proj_w, ipwb, 3 * 1024 * 1024);
    gemm_bt<float, __bf16, 0><<<dim3(24, 64), 256, 0, stream>>>(
        src, ipwb, in_proj_b, nullptr, nullptr, qkb, vb, 8192, 3072, 1024,
        1024);
    attn_flash<<<dim3(8, 128), 256, 0, stream>>>(qkb, vb, ctxb);
    cvt_kernel<<<512, 256, 0, stream>>>(out_w, owb, 1024 * 1024);
    gemm_bt<__bf16, __bf16, 1><<<dim3(8, 64), 256, 0, stream>>>(
        ctxb, owb, out_b, src, nullptr, yb, nullptr, 8192, 1024, 1024, 1024);
    ln_kernel<__bf16><<<8192, 256, 0, stream>>>(yb, g1, be1, xb);
    cvt_kernel<<<2048, 256, 0, stream>>>(w1, w1b, 4 * 1024 * 1024);
    cvt_kernel<<<2048, 256, 0, stream>>>(w2, w2b, 4 * 1024 * 1024);
    for (int qd = 0; qd < 4; ++qd) {
      gemm_bt<__bf16, __bf16, 2><<<dim3(8, 64), 256, 0, stream>>>(
          xb, w1b + (int64_t)qd * 1024 * 1024, b1 + qd * 1024, nullptr,
          nullptr, hb, nullptr, 8192, 1024, 1024, 1024);
      if (qd == 0)
        gemm_bt<__bf16, __bf16, 4><<<dim3(8, 64), 256, 0, stream>>>(
            hb, w2b + qd * 1024, b2, nullptr, xb, zb, nullptr, 8192, 1024,
            1024, 4096);
      else
        gemm_bt<__bf16, __bf16, 3><<<dim3(8, 64), 256, 0, stream>>>(
            hb, w2b + qd * 1024, nullptr, nullptr, zb, zb, nullptr, 8192, 1024,
            1024, 4096);
    }
    ln_kernel<float><<<8192, 256, 0, stream>>>(zb, g2, be2, (float*)d_out);
  }
}

// Round 8
// 570.081 us; speedup vs baseline: 1.2117x; 1.2117x over previous
//
#include <hip/hip_runtime.h>
#include <hip/hip_bf16.h>
#include <stdint.h>

typedef __bf16 bf16x8 __attribute__((ext_vector_type(8)));
typedef __bf16 bf16x4 __attribute__((ext_vector_type(4)));
typedef float floatx4 __attribute__((ext_vector_type(4)));

typedef __attribute__((address_space(1))) void gvoid;
typedef __attribute__((address_space(3))) void lvoid;

__device__ __forceinline__ void async_load16(const __bf16* g, __bf16* l) {
  __builtin_amdgcn_global_load_lds((gvoid*)g, (lvoid*)l, 16, 0, 0);
}

__device__ __forceinline__ bf16x8 ld8(const float* p) {
  const floatx4 a = *(const floatx4*)p;
  const floatx4 b = *(const floatx4*)(p + 4);
  bf16x8 r;
  r[0] = (__bf16)a[0]; r[1] = (__bf16)a[1];
  r[2] = (__bf16)a[2]; r[3] = (__bf16)a[3];
  r[4] = (__bf16)b[0]; r[5] = (__bf16)b[1];
  r[6] = (__bf16)b[2]; r[7] = (__bf16)b[3];
  return r;
}

// fp32 -> bf16 elementwise (n multiple of 2048)
__global__ __launch_bounds__(256) void cvt_kernel(const float* __restrict__ in,
                                                  __bf16* __restrict__ out,
                                                  int n) {
  const int i = (blockIdx.x * 256 + threadIdx.x) * 8;
  if (i < n) *(bf16x8*)(out + i) = ld8(in + i);
}

// ---------------------------------------------------------------------------
// gemm_db: 128x128 BK=32, 4 waves, LDS DOUBLE-BUFFERED minimum-2-phase loop
// (T3-lite, catalog-verified): stage tile t+1 at TOP of iter t, compute tile
// t, ONE __syncthreads at the end. Its implicit vmcnt(0)+lgkmcnt(0) drain
// lands AFTER the ds_read+MFMA phase -> stages get a full compute phase of
// lead (vs 0 in the old 2-barrier form). 32 KiB LDS keeps 2+ blocks/CU
// co-resident (the m114 overlap the R3 gemm128 lost).
// A fp32 path: register staging; ds_write tile t+1 at top (regs prefetched
// one iter earlier -> compiler's vmcnt wait sits a full iteration after
// issue), then global prefetch of tile t+2.
// WAR safety: iter-t reads of buf[cur] drain at the barrier (lgkmcnt(0))
// before iter t+1 overwrites buf[cur]; all waves' vmcnt(0) pass before any
// wave reads cross-wave-staged rows.
// EPI: 0 QKV (q cols scaled 0.125, vT scatter), 1 +bias+resf(fp32),
// 2 relu(+bias), 3 +resb(bf16), 4 +bias+resb(bf16).
// ---------------------------------------------------------------------------
constexpr int BM = 128, BN = 128, BK = 32;

template <typename AT, int EPI>
__global__ __launch_bounds__(256, 2) void gemm_db(
    const AT* __restrict__ A, const __bf16* __restrict__ Bt,
    const float* __restrict__ bias, const float* __restrict__ resf,
    const __bf16* __restrict__ resb, __bf16* __restrict__ o0,
    __bf16* __restrict__ o2, int M, int N, int K, int ldb) {
  constexpr bool AF = sizeof(AT) == 4;
  __shared__ __align__(16) __bf16 As[2][BM * BK];  // 2 x 8 KiB
  __shared__ __align__(16) __bf16 Bs[2][BN * BK];  // 2 x 8 KiB
  const int tid = threadIdx.x;
  const int w = tid >> 6;
  const int lane = tid & 63;
  const int l16 = lane & 15;
  const int quad = lane >> 4;
  const int wm = (w & 1) * 64;
  const int wn = (w >> 1) * 64;
  const int bm = blockIdx.y * BM;
  const int bn = blockIdx.x * BN;

  floatx4 acc[4][4];
#pragma unroll
  for (int i = 0; i < 4; ++i)
#pragma unroll
    for (int j = 0; j < 4; ++j) acc[i][j] = (floatx4){0.f, 0.f, 0.f, 0.f};

  const int srow = tid >> 2, scol = (tid & 3) * 8;   // fp32 reg-stage map
  const int arow = lane >> 2, acol = (lane & 3) * 8; // bf16 async map
  const AT* Ag;
  if constexpr (AF) Ag = A + (int64_t)(bm + srow) * K + scol;
  else Ag = A + (int64_t)(bm + w * 32 + arow) * K + acol;
  const __bf16* Bg = Bt + (int64_t)(bn + w * 32 + arow) * ldb + acol;

  // prologue: stage tile 0 into buf 0; prefetch tile 1 regs (fp32 path)
  bf16x8 a0, a1;
  if constexpr (AF) {
    a0 = ld8(Ag);
    a1 = ld8(Ag + (int64_t)64 * K);
    *(bf16x8*)(As[0] + tid * 8) = a0;
    *(bf16x8*)(As[0] + 2048 + tid * 8) = a1;
    if (BK < K) {
      a0 = ld8(Ag + BK);
      a1 = ld8(Ag + BK + (int64_t)64 * K);
    }
  } else {
    __bf16* AsW = As[0] + (w * 32) * BK;
    async_load16(Ag, AsW);
    async_load16(Ag + 16 * K, AsW + 16 * BK);
  }
  {
    __bf16* BsW = Bs[0] + (w * 32) * BK;
    async_load16(Bg, BsW);
    async_load16(Bg + 16 * ldb, BsW + 16 * BK);
  }
  __syncthreads();

  int cur = 0;
  for (int k0 = 0; k0 < K; k0 += BK) {
    const bool more = (k0 + BK) < K;
    // ---- stage tile t+1 into buf[cur^1] (issued BEFORE compute) ----
    if (more) {
      if constexpr (AF) {
        *(bf16x8*)(As[cur ^ 1] + tid * 8) = a0;         // waits vmcnt on regs
        *(bf16x8*)(As[cur ^ 1] + 2048 + tid * 8) = a1;  // (issued 1 iter ago)
        if (k0 + 2 * BK < K) {
          a0 = ld8(Ag + k0 + 2 * BK);
          a1 = ld8(Ag + k0 + 2 * BK + (int64_t)64 * K);
        }
      } else {
        __bf16* AsW = As[cur ^ 1] + (w * 32) * BK;
        async_load16(Ag + k0 + BK, AsW);
        async_load16(Ag + k0 + BK + 16 * K, AsW + 16 * BK);
      }
      __bf16* BsW = Bs[cur ^ 1] + (w * 32) * BK;
      async_load16(Bg + k0 + BK, BsW);
      async_load16(Bg + k0 + BK + 16 * ldb, BsW + 16 * BK);
    }
    // ---- compute tile t from buf[cur] ----
    bf16x8 af[4], bfr[4];
#pragma unroll
    for (int i = 0; i < 4; ++i) {
      af[i] = *(const bf16x8*)(As[cur] + (wm + i * 16 + l16) * BK + quad * 8);
      bfr[i] = *(const bf16x8*)(Bs[cur] + (wn + i * 16 + l16) * BK + quad * 8);
    }
#pragma unroll
    for (int mi = 0; mi < 4; ++mi)
#pragma unroll
      for (int ni = 0; ni < 4; ++ni)
        acc[mi][ni] = __builtin_amdgcn_mfma_f32_16x16x32_bf16(
            af[mi], bfr[ni], acc[mi][ni], 0, 0, 0);
    // single barrier: implicit vmcnt(0)+lgkmcnt(0) drain sits AFTER compute
    __syncthreads();
    cur ^= 1;
  }

  // epilogue: C/D layout col = lane&15, row = quad*4 + reg  [m89-verified]
#pragma unroll
  for (int ni = 0; ni < 4; ++ni) {
    const int gn = bn + wn + ni * 16 + l16;
    const float bv = (EPI == 3) ? 0.f : bias[gn];
#pragma unroll
    for (int mi = 0; mi < 4; ++mi) {
#pragma unroll
      for (int r = 0; r < 4; ++r) {
        const int gm = bm + wm + mi * 16 + quad * 4 + r;
        float v = acc[mi][ni][r] + bv;
        if (EPI == 0) {
          if (gn < 2048) {
            o0[(int64_t)gm * 2048 + gn] = (__bf16)(gn < 1024 ? v * 0.125f : v);
          } else {
            const int nn = gn - 2048, hh = nn >> 6, d = nn & 63;
            const int s = gm >> 3, b = gm & 7;  // m = s*8 + b
            o2[((b * 16 + hh) * 64 + d) * 1024 + s] = (__bf16)v;
          }
        } else {
          if (EPI == 1) v += resf[(int64_t)gm * N + gn];
          if (EPI == 3 || EPI == 4) v += (float)resb[(int64_t)gm * N + gn];
          if (EPI == 2) v = fmaxf(v, 0.f);
          o0[(int64_t)gm * N + gn] = (__bf16)v;
        }
      }
    }
  }
}

// ---------------------------------------------------------------------------
// Flash attention, no-max softmax. Block = (bh, 128 Q rows); wave = 32 rows.
// K/V chunks (32 t) staged via global_load_lds w16, double-buffered (T14):
// one barrier per iteration, next chunk flies under compute. (R3-verified.)
// ---------------------------------------------------------------------------
__global__ __launch_bounds__(256) void attn_flash(
    const __bf16* __restrict__ qk, const __bf16* __restrict__ vT,
    __bf16* __restrict__ ctx) {
  constexpr int S = 1024, PSTR = 36;
  constexpr int ROWSTR = 8 * 2048;
  __shared__ __align__(16) __bf16 Kb[2][2048];
  __shared__ __align__(16) __bf16 Vb[2][2048];
  __shared__ __align__(16) __bf16 Pt[4][32 * PSTR];
  const int tid = threadIdx.x;
  const int w = tid >> 6;
  const int lane = tid & 63;
  const int l16 = lane & 15;
  const int quad = lane >> 4;
  const int bh = blockIdx.y, bidx = bh >> 4, h = bh & 15;
  const int qbase = blockIdx.x * 128 + w * 32;

  const __bf16* qp =
      qk + ((int64_t)(qbase + l16) * 8 + bidx) * 2048 + h * 64 + quad * 8;
  bf16x8 aq[2][2];
  aq[0][0] = *(const bf16x8*)qp;
  aq[0][1] = *(const bf16x8*)(qp + 32);
  aq[1][0] = *(const bf16x8*)(qp + 16 * ROWSTR);
  aq[1][1] = *(const bf16x8*)(qp + 16 * ROWSTR + 32);

  const __bf16* kg = qk + 1024 +
      ((int64_t)((w >> 1) * 16 + l16) * 8 + bidx) * 2048 + h * 64 +
      ((w & 1) * 4 + quad) * 8;
  const __bf16* vg =
      vT + ((int64_t)bh * 64 + w * 16 + l16) * 1024 + quad * 8;
  __bf16* pt = Pt[w];

  floatx4 o[2][4];
  float la[2][4];
#pragma unroll
  for (int rt = 0; rt < 2; ++rt)
#pragma unroll
    for (int j = 0; j < 4; ++j) {
      o[rt][j] = (floatx4){0.f, 0.f, 0.f, 0.f};
      la[rt][j] = 0.f;
    }

  async_load16(kg, Kb[0] + w * 512);
  async_load16(vg, Vb[0] + w * 512);
  int cur = 0;

  for (int t0 = 0; t0 < S; t0 += 32) {
    __syncthreads();
    if (t0 + 32 < S) {
      async_load16(kg + (int64_t)(t0 + 32) * ROWSTR, Kb[cur ^ 1] + w * 512);
      async_load16(vg + (t0 + 32), Vb[cur ^ 1] + w * 512);
    }

    bf16x8 kf[4], vv[4];
#pragma unroll
    for (int f = 0; f < 4; ++f) {
      kf[f] = *(const bf16x8*)(Kb[cur] + f * 512 + lane * 8);
      vv[f] = *(const bf16x8*)(Vb[cur] + f * 512 + lane * 8);
    }

    floatx4 s00 = (floatx4){0.f, 0.f, 0.f, 0.f};
    floatx4 s01 = (floatx4){0.f, 0.f, 0.f, 0.f};
    floatx4 s10 = (floatx4){0.f, 0.f, 0.f, 0.f};
    floatx4 s11 = (floatx4){0.f, 0.f, 0.f, 0.f};
    s00 = __builtin_amdgcn_mfma_f32_16x16x32_bf16(aq[0][0], kf[0], s00, 0, 0, 0);
    s00 = __builtin_amdgcn_mfma_f32_16x16x32_bf16(aq[0][1], kf[1], s00, 0, 0, 0);
    s01 = __builtin_amdgcn_mfma_f32_16x16x32_bf16(aq[0][0], kf[2], s01, 0, 0, 0);
    s01 = __builtin_amdgcn_mfma_f32_16x16x32_bf16(aq[0][1], kf[3], s01, 0, 0, 0);
    s10 = __builtin_amdgcn_mfma_f32_16x16x32_bf16(aq[1][0], kf[0], s10, 0, 0, 0);
    s10 = __builtin_amdgcn_mfma_f32_16x16x32_bf16(aq[1][1], kf[1], s10, 0, 0, 0);
    s11 = __builtin_amdgcn_mfma_f32_16x16x32_bf16(aq[1][0], kf[2], s11, 0, 0, 0);
    s11 = __builtin_amdgcn_mfma_f32_16x16x32_bf16(aq[1][1], kf[3], s11, 0, 0, 0);

#pragma unroll
    for (int r = 0; r < 4; ++r) {
      const int row0 = (quad * 4 + r) * PSTR;
      const float p00 = __expf(s00[r]);
      const float p01 = __expf(s01[r]);
      la[0][r] += p00 + p01;
      pt[row0 + l16] = (__bf16)p00;
      pt[row0 + 16 + l16] = (__bf16)p01;
      const int row1 = (16 + quad * 4 + r) * PSTR;
      const float p10 = __expf(s10[r]);
      const float p11 = __expf(s11[r]);
      la[1][r] += p10 + p11;
      pt[row1 + l16] = (__bf16)p10;
      pt[row1 + 16 + l16] = (__bf16)p11;
    }
    const bf16x8 pa0 = *(const bf16x8*)(pt + l16 * PSTR + quad * 8);
    const bf16x8 pa1 = *(const bf16x8*)(pt + (16 + l16) * PSTR + quad * 8);
#pragma unroll
    for (int j = 0; j < 4; ++j) {
      o[0][j] = __builtin_amdgcn_mfma_f32_16x16x32_bf16(pa0, vv[j], o[0][j], 0, 0, 0);
      o[1][j] = __builtin_amdgcn_mfma_f32_16x16x32_bf16(pa1, vv[j], o[1][j], 0, 0, 0);
    }
    cur ^= 1;
  }

#pragma unroll
  for (int rt = 0; rt < 2; ++rt)
#pragma unroll
    for (int r = 0; r < 4; ++r) {
      float s = la[rt][r];
      s += __shfl_xor(s, 1, 64);
      s += __shfl_xor(s, 2, 64);
      s += __shfl_xor(s, 4, 64);
      s += __shfl_xor(s, 8, 64);
      la[rt][r] = s;
    }
#pragma unroll
  for (int rt = 0; rt < 2; ++rt)
#pragma unroll
    for (int j = 0; j < 4; ++j)
#pragma unroll
      for (int r = 0; r < 4; ++r) {
        const int row = qbase + rt * 16 + quad * 4 + r;
        const int gm = row * 8 + bidx;
        ctx[(int64_t)gm * 1024 + h * 64 + j * 16 + l16] =
            (__bf16)(o[rt][j][r] / la[rt][r]);
      }
}

// ---------------------------------------------------------------------------
// LayerNorm over last dim (1024). One block (256 thr) per row. Vectorized.
// ---------------------------------------------------------------------------
template <typename OutT>
__global__ __launch_bounds__(256) void ln_kernel(const __bf16* __restrict__ y,
                                                 const float* __restrict__ g,
                                                 const float* __restrict__ be,
                                                 OutT* __restrict__ out) {
  constexpr int D = 1024;
  const int row = blockIdx.x;
  const int tid = threadIdx.x;
  const __bf16* yr = y + (int64_t)row * D;
  const int c0 = tid * 4;
  const bf16x4 raw = *(const bf16x4*)(yr + c0);
  float v[4];
#pragma unroll
  for (int j = 0; j < 4; ++j) v[j] = (float)raw[j];
  float s = v[0] + v[1] + v[2] + v[3];
  float sq = v[0] * v[0] + v[1] * v[1] + v[2] * v[2] + v[3] * v[3];
#pragma unroll
  for (int off = 1; off < 64; off <<= 1) {
    s += __shfl_xor(s, off, 64);
    sq += __shfl_xor(sq, off, 64);
  }
  __shared__ float ls[4], lq[4];
  const int w = tid >> 6;
  if ((tid & 63) == 0) {
    ls[w] = s;
    lq[w] = sq;
  }
  __syncthreads();
  s = ls[0] + ls[1] + ls[2] + ls[3];
  sq = lq[0] + lq[1] + lq[2] + lq[3];
  const float mean = s * (1.f / D);
  const float var = sq * (1.f / D) - mean * mean;
  const float inv = rsqrtf(var + 1e-5f);
  const floatx4 gv = *(const floatx4*)(g + c0);
  const floatx4 bv = *(const floatx4*)(be + c0);
  if constexpr (sizeof(OutT) == 4) {
    floatx4 ov;
#pragma unroll
    for (int j = 0; j < 4; ++j) ov[j] = (v[j] - mean) * inv * gv[j] + bv[j];
    *(floatx4*)((float*)out + (int64_t)row * D + c0) = ov;
  } else {
    bf16x4 ov;
#pragma unroll
    for (int j = 0; j < 4; ++j)
      ov[j] = (__bf16)((v[j] - mean) * inv * gv[j] + bv[j]);
    *(bf16x4*)((__bf16*)out + (int64_t)row * D + c0) = ov;
  }
}

// ---------------------------------------------------------------------------
// Memory map, big path (ws >= 48 MiB; d_out 32 MiB doubles as scratch):
//   QKV       qk ws[0,32)  srcb ws[32,48)   vT out[0,16)  ipwb out[16,22)
//   attn      qk (r)                        ctx -> out[16,32)
//   out-proj  owb ws[0,2)  y ws[2,18)       ctx (r), src (r)
//   LN1       y (r)                         x -> out[0,16)
//   FFN       z ws[0,16)  h ws[16,48)       x (r), w1b out[16,24), w2b out[24,32)
//             2 N-halves: h=relu(x@w1h^T+b1h) [8192,2048]; z (+)= h@w2h^T (+b2+x)
//   LN2       z (r)                         d_out fp32 [0,32)
// Grids (gemm_db 128x128, 2+ blocks/CU): QKV (24,64)=1536, out-proj
// (8,64)=512, G1 (16,64)=1024, G2 (8,64)=512 — all full 512-block rounds.
// ---------------------------------------------------------------------------
extern "C" void kernel_launch(void* const* d_in, const int* in_sizes, int n_in,
                              void* d_out, int out_size, void* d_ws,
                              size_t ws_size, hipStream_t stream) {
  const float* src = (const float*)d_in[0];        // [8192,1024]
  const float* in_proj_w = (const float*)d_in[1];  // [3072,1024]
  const float* in_proj_b = (const float*)d_in[2];
  const float* out_w = (const float*)d_in[3];      // [1024,1024]
  const float* out_b = (const float*)d_in[4];
  const float* w1 = (const float*)d_in[5];         // [4096,1024]
  const float* b1 = (const float*)d_in[6];
  const float* w2 = (const float*)d_in[7];         // [1024,4096]
  const float* b2 = (const float*)d_in[8];
  const float* g1 = (const float*)d_in[9];
  const float* be1 = (const float*)d_in[10];
  const float* g2 = (const float*)d_in[11];
  const float* be2 = (const float*)d_in[12];

  char* ws = (char*)d_ws;
  char* out8 = (char*)d_out;
  __bf16* qkb = (__bf16*)ws;                       // ws[0,32M)
  __bf16* vb = (__bf16*)out8;                      // out[0,16M)
  __bf16* ipwb = (__bf16*)(out8 + (16ull << 20));  // out[16,22M)
  __bf16* srcb = (__bf16*)(ws + (32ull << 20));    // ws[32,48M)
  __bf16* ctxb = (__bf16*)(out8 + (16ull << 20));  // out[16,32M)
  __bf16* owb = (__bf16*)ws;                       // ws[0,2M)
  __bf16* yb = (__bf16*)(ws + (2ull << 20));       // ws[2,18M)
  __bf16* xb = (__bf16*)out8;                      // out[0,16M)

  const bool big = ws_size >= ((size_t)48 << 20);

  if (big) {
    __bf16* w1b = (__bf16*)(out8 + (16ull << 20));   // out[16,24M)
    __bf16* w2b = (__bf16*)(out8 + (24ull << 20));   // out[24,32M)
    __bf16* hb = (__bf16*)(ws + (16ull << 20));      // ws[16,48M) [8192,2048]
    __bf16* zb = (__bf16*)ws;                        // ws[0,16M)

    // 0/1. weight + src converts, QKV projection
    cvt_kernel<<<1536, 256, 0, stream>>>(in_proj_w, ipwb, 3 * 1024 * 1024);
    cvt_kernel<<<4096, 256, 0, stream>>>(src, srcb, 8 * 1024 * 1024);
    gemm_db<__bf16, 0><<<dim3(24, 64), 256, 0, stream>>>(
        srcb, ipwb, in_proj_b, nullptr, nullptr, qkb, vb, 8192, 3072, 1024,
        1024);
    // 2. flash attention (ctx overwrites dead ipwb region)
    attn_flash<<<dim3(8, 128), 256, 0, stream>>>(qkb, vb, ctxb);
    // 3. out-proj + residual(src fp32)
    cvt_kernel<<<512, 256, 0, stream>>>(out_w, owb, 1024 * 1024);
    gemm_db<__bf16, 1><<<dim3(8, 64), 256, 0, stream>>>(
        ctxb, owb, out_b, src, nullptr, yb, nullptr, 8192, 1024, 1024, 1024);
    // 4. LN1 -> x (overwrites dead vT)
    ln_kernel<__bf16><<<8192, 256, 0, stream>>>(yb, g1, be1, xb);
    // 5. FFN weights -> bf16 (ctx region dead after out-proj)
    cvt_kernel<<<2048, 256, 0, stream>>>(w1, w1b, 4 * 1024 * 1024);
    cvt_kernel<<<2048, 256, 0, stream>>>(w2, w2b, 4 * 1024 * 1024);
    // 6. FFN in 2 N=2048 halves
    for (int q = 0; q < 2; ++q) {
      gemm_db<__bf16, 2><<<dim3(16, 64), 256, 0, stream>>>(
          xb, w1b + (int64_t)q * 2048 * 1024, b1 + q * 2048, nullptr, nullptr,
          hb, nullptr, 8192, 2048, 1024, 1024);
      if (q == 0)
        gemm_db<__bf16, 4><<<dim3(8, 64), 256, 0, stream>>>(
            hb, w2b + q * 2048, b2, nullptr, xb, zb, nullptr, 8192, 1024, 2048,
            4096);
      else
        gemm_db<__bf16, 3><<<dim3(8, 64), 256, 0, stream>>>(
            hb, w2b + q * 2048, nullptr, nullptr, zb, zb, nullptr, 8192, 1024,
            2048, 4096);
    }
    // 7. LN2 -> output (fp32)
    ln_kernel<float><<<8192, 256, 0, stream>>>(zb, g2, be2, (float*)d_out);
  } else {
    // fallback (ws 32M): fp32-A QKV, FFN in 4 N=1024 quarters
    __bf16* w1b = (__bf16*)ws;                       // ws[0,8M)
    __bf16* w2b = (__bf16*)(ws + (8ull << 20));      // ws[8,16M)
    __bf16* hb = (__bf16*)(out8 + (16ull << 20));    // out[16,32M)
    __bf16* zb = (__bf16*)(ws + (16ull << 20));      // ws[16,32M)

    cvt_kernel<<<1536, 256, 0, stream>>>(in_proj_w, ipwb, 3 * 1024 * 1024);
    gemm_db<float, 0><<<dim3(24, 64), 256, 0, stream>>>(
        src, ipwb, in_proj_b, nullptr, nullptr, qkb, vb, 8192, 3072, 1024,
        1024);
    attn_flash<<<dim3(8, 128), 256, 0, stream>>>(qkb, vb, ctxb);
    cvt_kernel<<<512, 256, 0, stream>>>(out_w, owb, 1024 * 1024);
    gemm_db<__bf16, 1><<<dim3(8, 64), 256, 0, stream>>>(
        ctxb, owb, out_b, src, nullptr, yb, nullptr, 8192, 1024, 1024, 1024);
    ln_kernel<__bf16><<<8192, 256, 0, stream>>>(yb, g1, be1, xb);
    cvt_kernel<<<2048, 256, 0, stream>>>(w1, w1b, 4 * 1024 * 1024);
    cvt_kernel<<<2048, 256, 0, stream>>>(w2, w2b, 4 * 1024 * 1024);
    for (int qd = 0; qd < 4; ++qd) {
      gemm_db<__bf16, 2><<<dim3(8, 64), 256, 0, stream>>>(
          xb, w1b + (int64_t)qd * 1024 * 1024, b1 + qd * 1024, nullptr,
          nullptr, hb, nullptr, 8192, 1024, 1024, 1024);
      if (qd == 0)
        gemm_db<__bf16, 4><<<dim3(8, 64), 256, 0, stream>>>(
            hb, w2b + qd * 1024, b2, nullptr, xb, zb, nullptr, 8192, 1024,
            1024, 4096);
      else
        gemm_db<__bf16, 3><<<dim3(8, 64), 256, 0, stream>>>(
            hb, w2b + qd * 1024, nullptr, nullptr, zb, zb, nullptr, 8192, 1024,
            1024, 4096);
    }
    ln_kernel<float><<<8192, 256, 0, stream>>>(zb, g2, be2, (float*)d_out);
  }
}

// Round 11
// 540.849 us; speedup vs baseline: 1.2772x; 1.0540x over previous
//
#include <hip/hip_runtime.h>
#include <hip/hip_bf16.h>
#include <stdint.h>

typedef __bf16 bf16x8 __attribute__((ext_vector_type(8)));
typedef __bf16 bf16x4 __attribute__((ext_vector_type(4)));
typedef float floatx4 __attribute__((ext_vector_type(4)));

typedef __attribute__((address_space(1))) void gvoid;
typedef __attribute__((address_space(3))) void lvoid;

__device__ __forceinline__ void async_load16(const __bf16* g, __bf16* l) {
  __builtin_amdgcn_global_load_lds((gvoid*)g, (lvoid*)l, 16, 0, 0);
}

__device__ __forceinline__ bf16x8 ld8(const float* p) {
  const floatx4 a = *(const floatx4*)p;
  const floatx4 b = *(const floatx4*)(p + 4);
  bf16x8 r;
  r[0] = (__bf16)a[0]; r[1] = (__bf16)a[1];
  r[2] = (__bf16)a[2]; r[3] = (__bf16)a[3];
  r[4] = (__bf16)b[0]; r[5] = (__bf16)b[1];
  r[6] = (__bf16)b[2]; r[7] = (__bf16)b[3];
  return r;
}

// fp32 -> bf16 elementwise (n multiple of 2048)
__global__ __launch_bounds__(256) void cvt_kernel(const float* __restrict__ in,
                                                  __bf16* __restrict__ out,
                                                  int n) {
  const int i = (blockIdx.x * 256 + threadIdx.x) * 8;
  if (i < n) *(bf16x8*)(out + i) = ld8(in + i);
}

// ---------------------------------------------------------------------------
// gemm_db64: 128x128, BK=64, double-buffered, ONE barrier per 64-K chunk.
// R8 A/B showed per-iteration cost (~2.5k cyc) is barrier-event-bound, not
// stage-placement-bound -> halve barrier events (16 iters vs 32 at K=1024).
// LDS [buf][kh][128x32] keeps each kh-plane in the VERIFIED conflict-free
// BK=32 layout (row stride 64B -> 2 lanes/bank, free per m136); a row-major
// [128][64] tile would be a 16-way conflict (G4). 64 KiB LDS -> 2 blocks/CU
// (R1 16KiB vs R8 32KiB both 102us -> cover saturates ~2 blocks; acceptable).
// Staging = R8's verified map run twice (col += kh*32). Hazards identical to
// R8's gemm_db: stage t+1 -> buf^1 at top; compute t; one __syncthreads
// (implicit vmcnt(0)+lgkmcnt(0)) orders RAW (stages landed) + WAR (reads of
// buf[cur] drained before next-iter overwrite).
// EPI: 0 QKV (q cols scaled 0.125, vT scatter), 1 +bias+resf(fp32),
// 2 relu(+bias), 3 +resb(bf16), 4 +bias+resb(bf16).
// ---------------------------------------------------------------------------
template <int EPI>
__global__ __launch_bounds__(256, 2) void gemm_db64(
    const __bf16* __restrict__ A, const __bf16* __restrict__ Bt,
    const float* __restrict__ bias, const float* __restrict__ resf,
    const __bf16* __restrict__ resb, __bf16* __restrict__ o0,
    __bf16* __restrict__ o2, int M, int N, int K, int ldb) {
  __shared__ __align__(16) __bf16 As[2][2][128 * 32];  // [buf][kh] 2x2x8KiB
  __shared__ __align__(16) __bf16 Bs[2][2][128 * 32];
  const int tid = threadIdx.x;
  const int w = tid >> 6;
  const int lane = tid & 63;
  const int l16 = lane & 15;
  const int quad = lane >> 4;
  const int wm = (w & 1) * 64;
  const int wn = (w >> 1) * 64;
  const int bm = blockIdx.y * 128;
  const int bn = blockIdx.x * 128;

  floatx4 acc[4][4];
#pragma unroll
  for (int i = 0; i < 4; ++i)
#pragma unroll
    for (int j = 0; j < 4; ++j) acc[i][j] = (floatx4){0.f, 0.f, 0.f, 0.f};

  const int arow = lane >> 2, acol = (lane & 3) * 8;  // granule map (verified)
  const __bf16* Ag = A + (int64_t)(bm + w * 32 + arow) * K + acol;
  const __bf16* Bg = Bt + (int64_t)(bn + w * 32 + arow) * ldb + acol;

  // stage one 64-K chunk (both kh planes) of tile at k0 into buf b
  auto STAGE = [&](int b, int k0) {
#pragma unroll
    for (int kh = 0; kh < 2; ++kh) {
      __bf16* AsW = As[b][kh] + (w * 32) * 32;
      async_load16(Ag + k0 + kh * 32, AsW);
      async_load16(Ag + k0 + kh * 32 + 16 * K, AsW + 16 * 32);
      __bf16* BsW = Bs[b][kh] + (w * 32) * 32;
      async_load16(Bg + k0 + kh * 32, BsW);
      async_load16(Bg + k0 + kh * 32 + 16 * ldb, BsW + 16 * 32);
    }
  };

  STAGE(0, 0);
  __syncthreads();

  int cur = 0;
  for (int k0 = 0; k0 < K; k0 += 64) {
    if (k0 + 64 < K) STAGE(cur ^ 1, k0 + 64);  // issued BEFORE compute
#pragma unroll
    for (int kh = 0; kh < 2; ++kh) {
      bf16x8 af[4], bfr[4];
#pragma unroll
      for (int i = 0; i < 4; ++i) {
        af[i] = *(const bf16x8*)(As[cur][kh] + (wm + i * 16 + l16) * 32 + quad * 8);
        bfr[i] = *(const bf16x8*)(Bs[cur][kh] + (wn + i * 16 + l16) * 32 + quad * 8);
      }
#pragma unroll
      for (int mi = 0; mi < 4; ++mi)
#pragma unroll
        for (int ni = 0; ni < 4; ++ni)
          acc[mi][ni] = __builtin_amdgcn_mfma_f32_16x16x32_bf16(
              af[mi], bfr[ni], acc[mi][ni], 0, 0, 0);
    }
    __syncthreads();  // single drain per 64-K chunk
    cur ^= 1;
  }

  // epilogue: C/D layout col = lane&15, row = quad*4 + reg  [m89-verified]
#pragma unroll
  for (int ni = 0; ni < 4; ++ni) {
    const int gn = bn + wn + ni * 16 + l16;
    const float bv = (EPI == 3) ? 0.f : bias[gn];
#pragma unroll
    for (int mi = 0; mi < 4; ++mi) {
#pragma unroll
      for (int r = 0; r < 4; ++r) {
        const int gm = bm + wm + mi * 16 + quad * 4 + r;
        float v = acc[mi][ni][r] + bv;
        if (EPI == 0) {
          if (gn < 2048) {
            o0[(int64_t)gm * 2048 + gn] = (__bf16)(gn < 1024 ? v * 0.125f : v);
          } else {
            const int nn = gn - 2048, hh = nn >> 6, d = nn & 63;
            const int s = gm >> 3, b = gm & 7;  // m = s*8 + b
            o2[((b * 16 + hh) * 64 + d) * 1024 + s] = (__bf16)v;
          }
        } else {
          if (EPI == 1) v += resf[(int64_t)gm * N + gn];
          if (EPI == 3 || EPI == 4) v += (float)resb[(int64_t)gm * N + gn];
          if (EPI == 2) v = fmaxf(v, 0.f);
          o0[(int64_t)gm * N + gn] = (__bf16)v;
        }
      }
    }
  }
}

// ---------------------------------------------------------------------------
// gemm_db: R8-verified 128x128 BK=32 double-buffered loop (fallback path).
// ---------------------------------------------------------------------------
constexpr int BM = 128, BN = 128, BK = 32;

template <typename AT, int EPI>
__global__ __launch_bounds__(256, 2) void gemm_db(
    const AT* __restrict__ A, const __bf16* __restrict__ Bt,
    const float* __restrict__ bias, const float* __restrict__ resf,
    const __bf16* __restrict__ resb, __bf16* __restrict__ o0,
    __bf16* __restrict__ o2, int M, int N, int K, int ldb) {
  constexpr bool AF = sizeof(AT) == 4;
  __shared__ __align__(16) __bf16 As[2][BM * BK];
  __shared__ __align__(16) __bf16 Bs[2][BN * BK];
  const int tid = threadIdx.x;
  const int w = tid >> 6;
  const int lane = tid & 63;
  const int l16 = lane & 15;
  const int quad = lane >> 4;
  const int wm = (w & 1) * 64;
  const int wn = (w >> 1) * 64;
  const int bm = blockIdx.y * BM;
  const int bn = blockIdx.x * BN;

  floatx4 acc[4][4];
#pragma unroll
  for (int i = 0; i < 4; ++i)
#pragma unroll
    for (int j = 0; j < 4; ++j) acc[i][j] = (floatx4){0.f, 0.f, 0.f, 0.f};

  const int srow = tid >> 2, scol = (tid & 3) * 8;
  const int arow = lane >> 2, acol = (lane & 3) * 8;
  const AT* Ag;
  if constexpr (AF) Ag = A + (int64_t)(bm + srow) * K + scol;
  else Ag = A + (int64_t)(bm + w * 32 + arow) * K + acol;
  const __bf16* Bg = Bt + (int64_t)(bn + w * 32 + arow) * ldb + acol;

  bf16x8 a0, a1;
  if constexpr (AF) {
    a0 = ld8(Ag);
    a1 = ld8(Ag + (int64_t)64 * K);
    *(bf16x8*)(As[0] + tid * 8) = a0;
    *(bf16x8*)(As[0] + 2048 + tid * 8) = a1;
    if (BK < K) {
      a0 = ld8(Ag + BK);
      a1 = ld8(Ag + BK + (int64_t)64 * K);
    }
  } else {
    __bf16* AsW = As[0] + (w * 32) * BK;
    async_load16(Ag, AsW);
    async_load16(Ag + 16 * K, AsW + 16 * BK);
  }
  {
    __bf16* BsW = Bs[0] + (w * 32) * BK;
    async_load16(Bg, BsW);
    async_load16(Bg + 16 * ldb, BsW + 16 * BK);
  }
  __syncthreads();

  int cur = 0;
  for (int k0 = 0; k0 < K; k0 += BK) {
    const bool more = (k0 + BK) < K;
    if (more) {
      if constexpr (AF) {
        *(bf16x8*)(As[cur ^ 1] + tid * 8) = a0;
        *(bf16x8*)(As[cur ^ 1] + 2048 + tid * 8) = a1;
        if (k0 + 2 * BK < K) {
          a0 = ld8(Ag + k0 + 2 * BK);
          a1 = ld8(Ag + k0 + 2 * BK + (int64_t)64 * K);
        }
      } else {
        __bf16* AsW = As[cur ^ 1] + (w * 32) * BK;
        async_load16(Ag + k0 + BK, AsW);
        async_load16(Ag + k0 + BK + 16 * K, AsW + 16 * BK);
      }
      __bf16* BsW = Bs[cur ^ 1] + (w * 32) * BK;
      async_load16(Bg + k0 + BK, BsW);
      async_load16(Bg + k0 + BK + 16 * ldb, BsW + 16 * BK);
    }
    bf16x8 af[4], bfr[4];
#pragma unroll
    for (int i = 0; i < 4; ++i) {
      af[i] = *(const bf16x8*)(As[cur] + (wm + i * 16 + l16) * BK + quad * 8);
      bfr[i] = *(const bf16x8*)(Bs[cur] + (wn + i * 16 + l16) * BK + quad * 8);
    }
#pragma unroll
    for (int mi = 0; mi < 4; ++mi)
#pragma unroll
      for (int ni = 0; ni < 4; ++ni)
        acc[mi][ni] = __builtin_amdgcn_mfma_f32_16x16x32_bf16(
            af[mi], bfr[ni], acc[mi][ni], 0, 0, 0);
    __syncthreads();
    cur ^= 1;
  }

#pragma unroll
  for (int ni = 0; ni < 4; ++ni) {
    const int gn = bn + wn + ni * 16 + l16;
    const float bv = (EPI == 3) ? 0.f : bias[gn];
#pragma unroll
    for (int mi = 0; mi < 4; ++mi) {
#pragma unroll
      for (int r = 0; r < 4; ++r) {
        const int gm = bm + wm + mi * 16 + quad * 4 + r;
        float v = acc[mi][ni][r] + bv;
        if (EPI == 0) {
          if (gn < 2048) {
            o0[(int64_t)gm * 2048 + gn] = (__bf16)(gn < 1024 ? v * 0.125f : v);
          } else {
            const int nn = gn - 2048, hh = nn >> 6, d = nn & 63;
            const int s = gm >> 3, b = gm & 7;
            o2[((b * 16 + hh) * 64 + d) * 1024 + s] = (__bf16)v;
          }
        } else {
          if (EPI == 1) v += resf[(int64_t)gm * N + gn];
          if (EPI == 3 || EPI == 4) v += (float)resb[(int64_t)gm * N + gn];
          if (EPI == 2) v = fmaxf(v, 0.f);
          o0[(int64_t)gm * N + gn] = (__bf16)v;
        }
      }
    }
  }
}

// ---------------------------------------------------------------------------
// Flash attention, no-max softmax. Block = (bh, 128 Q rows); wave = 32 rows.
// K/V chunks (32 t) staged via global_load_lds w16, double-buffered (T14).
// ---------------------------------------------------------------------------
__global__ __launch_bounds__(256) void attn_flash(
    const __bf16* __restrict__ qk, const __bf16* __restrict__ vT,
    __bf16* __restrict__ ctx) {
  constexpr int S = 1024, PSTR = 36;
  constexpr int ROWSTR = 8 * 2048;
  __shared__ __align__(16) __bf16 Kb[2][2048];
  __shared__ __align__(16) __bf16 Vb[2][2048];
  __shared__ __align__(16) __bf16 Pt[4][32 * PSTR];
  const int tid = threadIdx.x;
  const int w = tid >> 6;
  const int lane = tid & 63;
  const int l16 = lane & 15;
  const int quad = lane >> 4;
  const int bh = blockIdx.y, bidx = bh >> 4, h = bh & 15;
  const int qbase = blockIdx.x * 128 + w * 32;

  const __bf16* qp =
      qk + ((int64_t)(qbase + l16) * 8 + bidx) * 2048 + h * 64 + quad * 8;
  bf16x8 aq[2][2];
  aq[0][0] = *(const bf16x8*)qp;
  aq[0][1] = *(const bf16x8*)(qp + 32);
  aq[1][0] = *(const bf16x8*)(qp + 16 * ROWSTR);
  aq[1][1] = *(const bf16x8*)(qp + 16 * ROWSTR + 32);

  const __bf16* kg = qk + 1024 +
      ((int64_t)((w >> 1) * 16 + l16) * 8 + bidx) * 2048 + h * 64 +
      ((w & 1) * 4 + quad) * 8;
  const __bf16* vg =
      vT + ((int64_t)bh * 64 + w * 16 + l16) * 1024 + quad * 8;
  __bf16* pt = Pt[w];

  floatx4 o[2][4];
  float la[2][4];
#pragma unroll
  for (int rt = 0; rt < 2; ++rt)
#pragma unroll
    for (int j = 0; j < 4; ++j) {
      o[rt][j] = (floatx4){0.f, 0.f, 0.f, 0.f};
      la[rt][j] = 0.f;
    }

  async_load16(kg, Kb[0] + w * 512);
  async_load16(vg, Vb[0] + w * 512);
  int cur = 0;

  for (int t0 = 0; t0 < S; t0 += 32) {
    __syncthreads();
    if (t0 + 32 < S) {
      async_load16(kg + (int64_t)(t0 + 32) * ROWSTR, Kb[cur ^ 1] + w * 512);
      async_load16(vg + (t0 + 32), Vb[cur ^ 1] + w * 512);
    }

    bf16x8 kf[4], vv[4];
#pragma unroll
    for (int f = 0; f < 4; ++f) {
      kf[f] = *(const bf16x8*)(Kb[cur] + f * 512 + lane * 8);
      vv[f] = *(const bf16x8*)(Vb[cur] + f * 512 + lane * 8);
    }

    floatx4 s00 = (floatx4){0.f, 0.f, 0.f, 0.f};
    floatx4 s01 = (floatx4){0.f, 0.f, 0.f, 0.f};
    floatx4 s10 = (floatx4){0.f, 0.f, 0.f, 0.f};
    floatx4 s11 = (floatx4){0.f, 0.f, 0.f, 0.f};
    s00 = __builtin_amdgcn_mfma_f32_16x16x32_bf16(aq[0][0], kf[0], s00, 0, 0, 0);
    s00 = __builtin_amdgcn_mfma_f32_16x16x32_bf16(aq[0][1], kf[1], s00, 0, 0, 0);
    s01 = __builtin_amdgcn_mfma_f32_16x16x32_bf16(aq[0][0], kf[2], s01, 0, 0, 0);
    s01 = __builtin_amdgcn_mfma_f32_16x16x32_bf16(aq[0][1], kf[3], s01, 0, 0, 0);
    s10 = __builtin_amdgcn_mfma_f32_16x16x32_bf16(aq[1][0], kf[0], s10, 0, 0, 0);
    s10 = __builtin_amdgcn_mfma_f32_16x16x32_bf16(aq[1][1], kf[1], s10, 0, 0, 0);
    s11 = __builtin_amdgcn_mfma_f32_16x16x32_bf16(aq[1][0], kf[2], s11, 0, 0, 0);
    s11 = __builtin_amdgcn_mfma_f32_16x16x32_bf16(aq[1][1], kf[3], s11, 0, 0, 0);

#pragma unroll
    for (int r = 0; r < 4; ++r) {
      const int row0 = (quad * 4 + r) * PSTR;
      const float p00 = __expf(s00[r]);
      const float p01 = __expf(s01[r]);
      la[0][r] += p00 + p01;
      pt[row0 + l16] = (__bf16)p00;
      pt[row0 + 16 + l16] = (__bf16)p01;
      const int row1 = (16 + quad * 4 + r) * PSTR;
      const float p10 = __expf(s10[r]);
      const float p11 = __expf(s11[r]);
      la[1][r] += p10 + p11;
      pt[row1 + l16] = (__bf16)p10;
      pt[row1 + 16 + l16] = (__bf16)p11;
    }
    const bf16x8 pa0 = *(const bf16x8*)(pt + l16 * PSTR + quad * 8);
    const bf16x8 pa1 = *(const bf16x8*)(pt + (16 + l16) * PSTR + quad * 8);
#pragma unroll
    for (int j = 0; j < 4; ++j) {
      o[0][j] = __builtin_amdgcn_mfma_f32_16x16x32_bf16(pa0, vv[j], o[0][j], 0, 0, 0);
      o[1][j] = __builtin_amdgcn_mfma_f32_16x16x32_bf16(pa1, vv[j], o[1][j], 0, 0, 0);
    }
    cur ^= 1;
  }

#pragma unroll
  for (int rt = 0; rt < 2; ++rt)
#pragma unroll
    for (int r = 0; r < 4; ++r) {
      float s = la[rt][r];
      s += __shfl_xor(s, 1, 64);
      s += __shfl_xor(s, 2, 64);
      s += __shfl_xor(s, 4, 64);
      s += __shfl_xor(s, 8, 64);
      la[rt][r] = s;
    }
#pragma unroll
  for (int rt = 0; rt < 2; ++rt)
#pragma unroll
    for (int j = 0; j < 4; ++j)
#pragma unroll
      for (int r = 0; r < 4; ++r) {
        const int row = qbase + rt * 16 + quad * 4 + r;
        const int gm = row * 8 + bidx;
        ctx[(int64_t)gm * 1024 + h * 64 + j * 16 + l16] =
            (__bf16)(o[rt][j][r] / la[rt][r]);
      }
}

// ---------------------------------------------------------------------------
// LayerNorm over last dim (1024). One block (256 thr) per row. Vectorized.
// ---------------------------------------------------------------------------
template <typename OutT>
__global__ __launch_bounds__(256) void ln_kernel(const __bf16* __restrict__ y,
                                                 const float* __restrict__ g,
                                                 const float* __restrict__ be,
                                                 OutT* __restrict__ out) {
  constexpr int D = 1024;
  const int row = blockIdx.x;
  const int tid = threadIdx.x;
  const __bf16* yr = y + (int64_t)row * D;
  const int c0 = tid * 4;
  const bf16x4 raw = *(const bf16x4*)(yr + c0);
  float v[4];
#pragma unroll
  for (int j = 0; j < 4; ++j) v[j] = (float)raw[j];
  float s = v[0] + v[1] + v[2] + v[3];
  float sq = v[0] * v[0] + v[1] * v[1] + v[2] * v[2] + v[3] * v[3];
#pragma unroll
  for (int off = 1; off < 64; off <<= 1) {
    s += __shfl_xor(s, off, 64);
    sq += __shfl_xor(sq, off, 64);
  }
  __shared__ float ls[4], lq[4];
  const int w = tid >> 6;
  if ((tid & 63) == 0) {
    ls[w] = s;
    lq[w] = sq;
  }
  __syncthreads();
  s = ls[0] + ls[1] + ls[2] + ls[3];
  sq = lq[0] + lq[1] + lq[2] + lq[3];
  const float mean = s * (1.f / D);
  const float var = sq * (1.f / D) - mean * mean;
  const float inv = rsqrtf(var + 1e-5f);
  const floatx4 gv = *(const floatx4*)(g + c0);
  const floatx4 bv = *(const floatx4*)(be + c0);
  if constexpr (sizeof(OutT) == 4) {
    floatx4 ov;
#pragma unroll
    for (int j = 0; j < 4; ++j) ov[j] = (v[j] - mean) * inv * gv[j] + bv[j];
    *(floatx4*)((float*)out + (int64_t)row * D + c0) = ov;
  } else {
    bf16x4 ov;
#pragma unroll
    for (int j = 0; j < 4; ++j)
      ov[j] = (__bf16)((v[j] - mean) * inv * gv[j] + bv[j]);
    *(bf16x4*)((__bf16*)out + (int64_t)row * D + c0) = ov;
  }
}

// ---------------------------------------------------------------------------
// Memory map, big path (ws >= 48 MiB; d_out 32 MiB doubles as scratch):
//   QKV       qk ws[0,32)  srcb ws[32,48)   vT out[0,16)  ipwb out[16,22)
//   attn      qk (r)                        ctx -> out[16,32)
//   out-proj  owb ws[0,2)  y ws[2,18)       ctx (r), src (r)
//   LN1       y (r)                         x -> out[0,16)
//   FFN       z ws[0,16)  h ws[16,48)       x (r), w1b out[16,24), w2b out[24,32)
//             2 N-halves: h=relu(x@w1h^T+b1h) [8192,2048]; z (+)= h@w2h^T (+b2+x)
//   LN2       z (r)                         d_out fp32 [0,32)
// Grids (128x128 tiles): QKV (24,64)=1536, out-proj (8,64)=512,
// G1 (16,64)=1024, G2 (8,64)=512 — all full 512-block rounds.
// ---------------------------------------------------------------------------
extern "C" void kernel_launch(void* const* d_in, const int* in_sizes, int n_in,
                              void* d_out, int out_size, void* d_ws,
                              size_t ws_size, hipStream_t stream) {
  const float* src = (const float*)d_in[0];        // [8192,1024]
  const float* in_proj_w = (const float*)d_in[1];  // [3072,1024]
  const float* in_proj_b = (const float*)d_in[2];
  const float* out_w = (const float*)d_in[3];      // [1024,1024]
  const float* out_b = (const float*)d_in[4];
  const float* w1 = (const float*)d_in[5];         // [4096,1024]
  const float* b1 = (const float*)d_in[6];
  const float* w2 = (const float*)d_in[7];         // [1024,4096]
  const float* b2 = (const float*)d_in[8];
  const float* g1 = (const float*)d_in[9];
  const float* be1 = (const float*)d_in[10];
  const float* g2 = (const float*)d_in[11];
  const float* be2 = (const float*)d_in[12];

  char* ws = (char*)d_ws;
  char* out8 = (char*)d_out;
  __bf16* qkb = (__bf16*)ws;                       // ws[0,32M)
  __bf16* vb = (__bf16*)out8;                      // out[0,16M)
  __bf16* ipwb = (__bf16*)(out8 + (16ull << 20));  // out[16,22M)
  __bf16* srcb = (__bf16*)(ws + (32ull << 20));    // ws[32,48M)
  __bf16* ctxb = (__bf16*)(out8 + (16ull << 20));  // out[16,32M)
  __bf16* owb = (__bf16*)ws;                       // ws[0,2M)
  __bf16* yb = (__bf16*)(ws + (2ull << 20));       // ws[2,18M)
  __bf16* xb = (__bf16*)out8;                      // out[0,16M)

  const bool big = ws_size >= ((size_t)48 << 20);

  if (big) {
    __bf16* w1b = (__bf16*)(out8 + (16ull << 20));   // out[16,24M)
    __bf16* w2b = (__bf16*)(out8 + (24ull << 20));   // out[24,32M)
    __bf16* hb = (__bf16*)(ws + (16ull << 20));      // ws[16,48M) [8192,2048]
    __bf16* zb = (__bf16*)ws;                        // ws[0,16M)

    // 0/1. weight + src converts, QKV projection
    cvt_kernel<<<1536, 256, 0, stream>>>(in_proj_w, ipwb, 3 * 1024 * 1024);
    cvt_kernel<<<4096, 256, 0, stream>>>(src, srcb, 8 * 1024 * 1024);
    gemm_db64<0><<<dim3(24, 64), 256, 0, stream>>>(
        srcb, ipwb, in_proj_b, nullptr, nullptr, qkb, vb, 8192, 3072, 1024,
        1024);
    // 2. flash attention (ctx overwrites dead ipwb region)
    attn_flash<<<dim3(8, 128), 256, 0, stream>>>(qkb, vb, ctxb);
    // 3. out-proj + residual(src fp32)
    cvt_kernel<<<512, 256, 0, stream>>>(out_w, owb, 1024 * 1024);
    gemm_db64<1><<<dim3(8, 64), 256, 0, stream>>>(
        ctxb, owb, out_b, src, nullptr, yb, nullptr, 8192, 1024, 1024, 1024);
    // 4. LN1 -> x (overwrites dead vT)
    ln_kernel<__bf16><<<8192, 256, 0, stream>>>(yb, g1, be1, xb);
    // 5. FFN weights -> bf16 (ctx region dead after out-proj)
    cvt_kernel<<<2048, 256, 0, stream>>>(w1, w1b, 4 * 1024 * 1024);
    cvt_kernel<<<2048, 256, 0, stream>>>(w2, w2b, 4 * 1024 * 1024);
    // 6. FFN in 2 N=2048 halves
    for (int q = 0; q < 2; ++q) {
      gemm_db64<2><<<dim3(16, 64), 256, 0, stream>>>(
          xb, w1b + (int64_t)q * 2048 * 1024, b1 + q * 2048, nullptr, nullptr,
          hb, nullptr, 8192, 2048, 1024, 1024);
      if (q == 0)
        gemm_db64<4><<<dim3(8, 64), 256, 0, stream>>>(
            hb, w2b + q * 2048, b2, nullptr, xb, zb, nullptr, 8192, 1024, 2048,
            4096);
      else
        gemm_db64<3><<<dim3(8, 64), 256, 0, stream>>>(
            hb, w2b + q * 2048, nullptr, nullptr, zb, zb, nullptr, 8192, 1024,
            2048, 4096);
    }
    // 7. LN2 -> output (fp32)
    ln_kernel<float><<<8192, 256, 0, stream>>>(zb, g2, be2, (float*)d_out);
  } else {
    // fallback (ws 32M): fp32-A QKV, FFN in 4 N=1024 quarters (R8-verified)
    __bf16* w1b = (__bf16*)ws;                       // ws[0,8M)
    __bf16* w2b = (__bf16*)(ws + (8ull << 20));      // ws[8,16M)
    __bf16* hb = (__bf16*)(out8 + (16ull << 20));    // out[16,32M)
    __bf16* zb = (__bf16*)(ws + (16ull << 20));      // ws[16,32M)

    cvt_kernel<<<1536, 256, 0, stream>>>(in_proj_w, ipwb, 3 * 1024 * 1024);
    gemm_db<float, 0><<<dim3(24, 64), 256, 0, stream>>>(
        src, ipwb, in_proj_b, nullptr, nullptr, qkb, vb, 8192, 3072, 1024,
        1024);
    attn_flash<<<dim3(8, 128), 256, 0, stream>>>(qkb, vb, ctxb);
    cvt_kernel<<<512, 256, 0, stream>>>(out_w, owb, 1024 * 1024);
    gemm_db<__bf16, 1><<<dim3(8, 64), 256, 0, stream>>>(
        ctxb, owb, out_b, src, nullptr, yb, nullptr, 8192, 1024, 1024, 1024);
    ln_kernel<__bf16><<<8192, 256, 0, stream>>>(yb, g1, be1, xb);
    cvt_kernel<<<2048, 256, 0, stream>>>(w1, w1b, 4 * 1024 * 1024);
    cvt_kernel<<<2048, 256, 0, stream>>>(w2, w2b, 4 * 1024 * 1024);
    for (int qd = 0; qd < 4; ++qd) {
      gemm_db<__bf16, 2><<<dim3(8, 64), 256, 0, stream>>>(
          xb, w1b + (int64_t)qd * 1024 * 1024, b1 + qd * 1024, nullptr,
          nullptr, hb, nullptr, 8192, 1024, 1024, 1024);
      if (qd == 0)
        gemm_db<__bf16, 4><<<dim3(8, 64), 256, 0, stream>>>(
            hb, w2b + qd * 1024, b2, nullptr, xb, zb, nullptr, 8192, 1024,
            1024, 4096);
      else
        gemm_db<__bf16, 3><<<dim3(8, 64), 256, 0, stream>>>(
            hb, w2b + qd * 1024, nullptr, nullptr, zb, zb, nullptr, 8192, 1024,
            1024, 4096);
    }
    ln_kernel<float><<<8192, 256, 0, stream>>>(zb, g2, be2, (float*)d_out);
  }
}